// Round 13
// baseline (472.437 us; speedup 1.0000x reference)
//
#include <hip/hip_runtime.h>

#define NPTS 16384
#define GS   32                       // grid cells per axis
#define NC   (GS * GS * GS)           // 32768 cells
#define BBOX 4.0f                     // grid covers [-BBOX, BBOX]^3, clamped
#define H    (2.0f * BBOX / GS)       // 0.25 cell edge
#define INVH ((float)GS / (2.0f * BBOX))

__device__ __forceinline__ int cellco(float v) {
    int c = (int)floorf((v + BBOX) * INVH);
    return min(max(c, 0), GS - 1);
}

// ---- pass 1: per-cell histograms for both clouds -------------------------
__global__ void hist_k(const float* __restrict__ s, const float* __restrict__ t,
                       int* __restrict__ cntS, int* __restrict__ cntT) {
    int i = blockIdx.x * blockDim.x + threadIdx.x;
    if (i >= 2 * NPTS) return;
    int cloud = i >> 14, p = i & (NPTS - 1);
    const float* base = cloud ? t : s;
    float x = base[3 * p], y = base[3 * p + 1], z = base[3 * p + 2];
    int id = (cellco(x) * GS + cellco(y)) * GS + cellco(z);
    atomicAdd((cloud ? cntT : cntS) + id, 1);
}

// ---- pass 2: exclusive scan of both histograms (single block) ------------
#define SCT 1024
#define CPT (NC / SCT)                // 32 cells per thread
__global__ __launch_bounds__(SCT)
void scan_k(const int* __restrict__ cntS, const int* __restrict__ cntT,
            int* __restrict__ startS, int* __restrict__ startT,
            int* __restrict__ curS, int* __restrict__ curT) {
    __shared__ int2 part[SCT];
    int t = threadIdx.x;
    int a = 0, b = 0;
    for (int k = 0; k < CPT; ++k) { a += cntS[t * CPT + k]; b += cntT[t * CPT + k]; }
    part[t] = make_int2(a, b);
    __syncthreads();
    for (int off = 1; off < SCT; off <<= 1) {        // Hillis-Steele inclusive
        int2 add = (t >= off) ? part[t - off] : make_int2(0, 0);
        __syncthreads();
        part[t].x += add.x; part[t].y += add.y;
        __syncthreads();
    }
    int2 run = (t > 0) ? part[t - 1] : make_int2(0, 0);
    for (int k = 0; k < CPT; ++k) {
        int c = t * CPT + k;
        startS[c] = run.x; curS[c] = run.x;
        startT[c] = run.y; curT[c] = run.y;
        run.x += cntS[c];  run.y += cntT[c];
    }
    if (t == SCT - 1) { startS[NC] = run.x; startT[NC] = run.y; }
}

// ---- pass 3: scatter points into cell-sorted order (w = orig index) ------
__global__ void scatter_k(const float* __restrict__ s, const float* __restrict__ t,
                          int* __restrict__ curS, int* __restrict__ curT,
                          float4* __restrict__ sortedS, float4* __restrict__ sortedT) {
    int i = blockIdx.x * blockDim.x + threadIdx.x;
    if (i >= 2 * NPTS) return;
    int cloud = i >> 14, p = i & (NPTS - 1);
    const float* base = cloud ? t : s;
    float x = base[3 * p], y = base[3 * p + 1], z = base[3 * p + 2];
    int id = (cellco(x) * GS + cellco(y)) * GS + cellco(z);
    int pos = atomicAdd((cloud ? curT : curS) + id, 1);
    (cloud ? sortedT : sortedS)[pos] = make_float4(x, y, z, __int_as_float(p));
}

// ---- pass 4: exact NN via expanding Chebyshev shells ----------------------
// Bounds are conservative: ring r >= 1 min distance >= minwall + (r-1)*H;
// per-cell lower bound = exact distance to cell box, edge cells extended to
// infinity on the outer side (covers clamped outliers). Worst case the loop
// degenerates to scanning all cells -> still exact.
__global__ __launch_bounds__(64)
void query_k(const float4* __restrict__ sortedS, const float4* __restrict__ sortedT,
             const int* __restrict__ startS, const int* __restrict__ startT,
             float* __restrict__ out) {
    int i = blockIdx.x * blockDim.x + threadIdx.x;
    if (i >= 2 * NPTS) return;
    int cloud = i >> 14, j = i & (NPTS - 1);
    float4 qp = (cloud ? sortedT : sortedS)[j];       // sorted order: coherent waves
    const float4* __restrict__ pts  = cloud ? sortedS : sortedT;
    const int*    __restrict__ start = cloud ? startS : startT;

    float qx = qp.x, qy = qp.y, qz = qp.z;
    int cx = cellco(qx), cy = cellco(qy), cz = cellco(qz);
    float lox = -BBOX + cx * H, loy = -BBOX + cy * H, loz = -BBOX + cz * H;
    float minwall = fminf(fminf(fminf(qx - lox, lox + H - qx),
                                fminf(qy - loy, loy + H - qy)),
                          fminf(qz - loz, loz + H - qz));
    minwall = fmaxf(minwall, 0.0f);

    float best = 1e30f;
    for (int r = 0; r < GS; ++r) {
        if (r >= 1) {
            float lb = minwall + (float)(r - 1) * H;
            if (lb * lb >= best) break;
        }
        int x0 = max(cx - r, 0), x1 = min(cx + r, GS - 1);
        int y0 = max(cy - r, 0), y1 = min(cy + r, GS - 1);
        int z0 = max(cz - r, 0), z1 = min(cz + r, GS - 1);
        for (int ix = x0; ix <= x1; ++ix) {
            int ax = abs(ix - cx);
            float clx = -BBOX + ix * H;
            float dxl = (ix == 0)      ? -1.0f : clx - qx;       // edge -> -inf side
            float dxh = (ix == GS - 1) ? -1.0f : qx - (clx + H);
            float dx = fmaxf(0.0f, fmaxf(dxl, dxh));
            float dx2 = dx * dx;
            if (dx2 >= best) continue;
            for (int iy = y0; iy <= y1; ++iy) {
                int axy = max(ax, abs(iy - cy));
                float cly = -BBOX + iy * H;
                float dyl = (iy == 0)      ? -1.0f : cly - qy;
                float dyh = (iy == GS - 1) ? -1.0f : qy - (cly + H);
                float dy = fmaxf(0.0f, fmaxf(dyl, dyh));
                float dxy2 = fmaf(dy, dy, dx2);
                if (dxy2 >= best) continue;
                for (int iz = z0; iz <= z1; ++iz) {
                    if (max(axy, abs(iz - cz)) != r) continue;   // shell cells only
                    float clz = -BBOX + iz * H;
                    float dzl = (iz == 0)      ? -1.0f : clz - qz;
                    float dzh = (iz == GS - 1) ? -1.0f : qz - (clz + H);
                    float dz = fmaxf(0.0f, fmaxf(dzl, dzh));
                    float lb = fmaf(dz, dz, dxy2);
                    if (lb >= best) continue;
                    int c = (ix * GS + iy) * GS + iz;
                    int k1 = start[c + 1];
                    for (int k = start[c]; k < k1; ++k) {
                        float4 p = pts[k];
                        float ddx = qx - p.x, ddy = qy - p.y, ddz = qz - p.z;
                        float d = fmaf(ddx, ddx, fmaf(ddy, ddy, ddz * ddz));
                        best = fminf(best, d);
                    }
                }
            }
        }
    }
    out[cloud * NPTS + __float_as_int(qp.w)] = best;
}

extern "C" void kernel_launch(void* const* d_in, const int* in_sizes, int n_in,
                              void* d_out, int out_size, void* d_ws, size_t ws_size,
                              hipStream_t stream) {
    const float* s = (const float*)d_in[0];
    const float* t = (const float*)d_in[1];

    int* wsI = (int*)d_ws;
    int* cntS   = wsI;                 // NC
    int* cntT   = wsI + NC;            // NC
    int* startS = wsI + 2 * NC;        // NC+1
    int* startT = wsI + 3 * NC + 1;    // NC+1
    int* curS   = wsI + 4 * NC + 2;    // NC
    int* curT   = wsI + 5 * NC + 2;    // NC
    size_t off4 = ((size_t)6 * NC + 2 + 3) & ~(size_t)3;   // 16B-align
    float4* sortedS = (float4*)(wsI + off4);               // NPTS
    float4* sortedT = sortedS + NPTS;                      // NPTS

    hipMemsetAsync(cntS, 0, (size_t)2 * NC * sizeof(int), stream);  // hist zero each call
    hist_k<<<(2 * NPTS) / 256, 256, 0, stream>>>(s, t, cntS, cntT);
    scan_k<<<1, SCT, 0, stream>>>(cntS, cntT, startS, startT, curS, curT);
    scatter_k<<<(2 * NPTS) / 256, 256, 0, stream>>>(s, t, curS, curT, sortedS, sortedT);
    query_k<<<(2 * NPTS) / 64, 64, 0, stream>>>(sortedS, sortedT, startS, startT,
                                                (float*)d_out);
}

// Round 14
// 118.609 us; speedup vs baseline: 3.9832x; 3.9832x over previous
//
#include <hip/hip_runtime.h>

#define NPTS 16384
#define GS   32
#define NC   (GS * GS * GS)
#define BBOX 4.0f
#define H    0.25f
#define INVH 4.0f
#define RMAX 8
#define TABN 4913                 // 17^3 packed shell offsets, ring-sorted
#define QL   16                   // lanes per query

__device__ __forceinline__ int cellco(float v) {
    int c = (int)floorf((v + BBOX) * INVH);
    return min(max(c, 0), GS - 1);
}

// ---- pass 1: per-cell histograms --------------------------------------
__global__ void hist_k(const float* __restrict__ s, const float* __restrict__ t,
                       int* __restrict__ cntS, int* __restrict__ cntT) {
    int i = blockIdx.x * blockDim.x + threadIdx.x;
    int cloud = i >> 14, p = i & (NPTS - 1);
    const float* base = cloud ? t : s;
    float x = base[3 * p], y = base[3 * p + 1], z = base[3 * p + 2];
    int id = (cellco(x) * GS + cellco(y)) * GS + cellco(z);
    atomicAdd((cloud ? cntT : cntS) + id, 1);
}

// ---- pass 2: scan (int4 loads, int4 stores) + shell-table generation ----
__global__ __launch_bounds__(1024)
void scan_k(const int* __restrict__ cntS, const int* __restrict__ cntT,
            int* __restrict__ startS, int* __restrict__ startT,
            int* __restrict__ tab) {
    __shared__ int2 part[1024];
    __shared__ int ringc[RMAX + 1];
    int t = threadIdx.x;
    if (t <= RMAX) ringc[t] = 0;

    const int4* cS4 = (const int4*)cntS;
    const int4* cT4 = (const int4*)cntT;
    int4 bufS[8], bufT[8];
    int a = 0, b = 0;
#pragma unroll
    for (int k = 0; k < 8; ++k) {
        bufS[k] = cS4[t * 8 + k];
        bufT[k] = cT4[t * 8 + k];
        a += bufS[k].x + bufS[k].y + bufS[k].z + bufS[k].w;
        b += bufT[k].x + bufT[k].y + bufT[k].z + bufT[k].w;
    }
    part[t] = make_int2(a, b);
    __syncthreads();
    for (int off = 1; off < 1024; off <<= 1) {       // Hillis-Steele inclusive
        int2 add = (t >= off) ? part[t - off] : make_int2(0, 0);
        __syncthreads();
        part[t].x += add.x; part[t].y += add.y;
        __syncthreads();
    }
    int2 run = (t > 0) ? part[t - 1] : make_int2(0, 0);
    int4* sS4 = (int4*)startS;
    int4* sT4 = (int4*)startT;
#pragma unroll
    for (int k = 0; k < 8; ++k) {
        int4 o;
        o.x = run.x; run.x += bufS[k].x;
        o.y = run.x; run.x += bufS[k].y;
        o.z = run.x; run.x += bufS[k].z;
        o.w = run.x; run.x += bufS[k].w;
        sS4[t * 8 + k] = o;
        o.x = run.y; run.y += bufT[k].x;
        o.y = run.y; run.y += bufT[k].y;
        o.z = run.y; run.y += bufT[k].z;
        o.w = run.y; run.y += bufT[k].w;
        sT4[t * 8 + k] = o;
    }
    // shell table: offsets (dx,dy,dz) in [-8,8]^3 grouped by Chebyshev ring;
    // ring r occupies tab[(2r-1)^3 .. (2r+1)^3); order within ring arbitrary.
    for (unsigned idx = t; idx < TABN; idx += 1024) {
        unsigned q1 = idx / 289u, rem = idx - q1 * 289u;
        unsigned q2 = rem / 17u,  q3 = rem - q2 * 17u;
        int ring = max(max(abs((int)q1 - 8), abs((int)q2 - 8)), abs((int)q3 - 8));
        int pos = 0;
        if (ring > 0) {
            int w = 2 * ring - 1;
            pos = w * w * w + atomicAdd(&ringc[ring], 1);
        }
        tab[pos] = ((int)q1 << 10) | ((int)q2 << 5) | (int)q3;
    }
}

// ---- pass 3: destructive scatter (start[] becomes end[]) ----------------
__global__ void scatter_k(const float* __restrict__ s, const float* __restrict__ t,
                          int* __restrict__ startS, int* __restrict__ startT,
                          float4* __restrict__ sortedS, float4* __restrict__ sortedT) {
    int i = blockIdx.x * blockDim.x + threadIdx.x;
    int cloud = i >> 14, p = i & (NPTS - 1);
    const float* base = cloud ? t : s;
    float x = base[3 * p], y = base[3 * p + 1], z = base[3 * p + 2];
    int id = (cellco(x) * GS + cellco(y)) * GS + cellco(z);
    int pos = atomicAdd((cloud ? startT : startS) + id, 1);
    (cloud ? sortedT : sortedS)[pos] = make_float4(x, y, z, __int_as_float(p));
}

// ---- pass 4: exact NN, 16 lanes per query -------------------------------
__global__ __launch_bounds__(256)
void query_k(const float4* __restrict__ sortedS, const float4* __restrict__ sortedT,
             const int* __restrict__ endS, const int* __restrict__ endT,
             const int* __restrict__ cntS, const int* __restrict__ cntT,
             const int* __restrict__ tab, float* __restrict__ out) {
    int tid = blockIdx.x * blockDim.x + threadIdx.x;
    int q = tid >> 4, g = tid & (QL - 1);
    int cloud = q >> 14, j = q & (NPTS - 1);
    float4 qp = (cloud ? sortedT : sortedS)[j];      // sorted: coherent groups
    const float4* __restrict__ pts = cloud ? sortedS : sortedT;
    const int* __restrict__ end = cloud ? endS : endT;
    const int* __restrict__ cnt = cloud ? cntS : cntT;

    float qx = qp.x, qy = qp.y, qz = qp.z;
    int cx = cellco(qx), cy = cellco(qy), cz = cellco(qz);
    float minwall = fminf(fminf(fminf(qx - (-BBOX + cx * H), (-BBOX + (cx + 1) * H) - qx),
                                fminf(qy - (-BBOX + cy * H), (-BBOX + (cy + 1) * H) - qy)),
                          fminf(qz - (-BBOX + cz * H), (-BBOX + (cz + 1) * H) - qz));
    minwall = fmaxf(minwall, 0.0f);

    float best = 1e30f;

#define SCAN_CELL(ix, iy, iz)                                                  \
    {                                                                          \
        float clx = -BBOX + (ix) * H, cly = -BBOX + (iy) * H,                  \
              clz = -BBOX + (iz) * H;                                          \
        float dx = fmaxf(0.f, fmaxf((ix) == 0 ? -1.f : clx - qx,               \
                                    (ix) == GS - 1 ? -1.f : qx - clx - H));    \
        float dy = fmaxf(0.f, fmaxf((iy) == 0 ? -1.f : cly - qy,               \
                                    (iy) == GS - 1 ? -1.f : qy - cly - H));    \
        float dz = fmaxf(0.f, fmaxf((iz) == 0 ? -1.f : clz - qz,               \
                                    (iz) == GS - 1 ? -1.f : qz - clz - H));    \
        float lb = fmaf(dx, dx, fmaf(dy, dy, dz * dz));                        \
        if (lb < best) {                                                       \
            int c = ((ix) * GS + (iy)) * GS + (iz);                            \
            int e = end[c], k0 = e - cnt[c];                                   \
            for (int k = k0; k < e; ++k) {                                     \
                float4 p = pts[k];                                             \
                float ax = qx - p.x, ay = qy - p.y, az = qz - p.z;             \
                best = fminf(best, fmaf(ax, ax, fmaf(ay, ay, az * az)));       \
            }                                                                  \
        }                                                                      \
    }

    for (int r = 0; r < GS; ++r) {
        // group-uniform best + break check
        float bu = best;
        bu = fminf(bu, __shfl_xor(bu, 1, QL));
        bu = fminf(bu, __shfl_xor(bu, 2, QL));
        bu = fminf(bu, __shfl_xor(bu, 4, QL));
        bu = fminf(bu, __shfl_xor(bu, 8, QL));
        if (r >= 1) {
            float lb = minwall + (float)(r - 1) * H;
            if (lb * lb >= bu) break;
        }
        best = bu;

        if (r == 0) {                      // home cell: strided over 16 lanes
            int c = (cx * GS + cy) * GS + cz;
            int e = end[c], k0 = e - cnt[c];
            for (int k = k0 + g; k < e; k += QL) {
                float4 p = pts[k];
                float ax = qx - p.x, ay = qy - p.y, az = qz - p.z;
                best = fminf(best, fmaf(ax, ax, fmaf(ay, ay, az * az)));
            }
        } else if (r <= RMAX) {            // table-driven shell
            int w = 2 * r - 1, W = 2 * r + 1;
            int i0 = w * w * w, i1 = W * W * W;
            for (int idx = i0 + g; idx < i1; idx += QL) {
                int pk = tab[idx];
                int ix = cx + (pk >> 10) - 8;
                int iy = cy + ((pk >> 5) & 31) - 8;
                int iz = cz + (pk & 31) - 8;
                if ((unsigned)ix >= GS || (unsigned)iy >= GS || (unsigned)iz >= GS)
                    continue;
                SCAN_CELL(ix, iy, iz)
            }
        } else {                           // rare far rings: box walk + skip
            unsigned W = 2 * r + 1, W2 = W * W, tot = W2 * W;
            for (unsigned idx = g; idx < tot; idx += QL) {
                unsigned q1 = idx / W2, rem = idx - q1 * W2;
                unsigned q2 = rem / W, q3 = rem - q2 * W;
                int dxo = (int)q1 - r, dyo = (int)q2 - r, dzo = (int)q3 - r;
                if (max(max(abs(dxo), abs(dyo)), abs(dzo)) != r) continue;
                int ix = cx + dxo, iy = cy + dyo, iz = cz + dzo;
                if ((unsigned)ix >= GS || (unsigned)iy >= GS || (unsigned)iz >= GS)
                    continue;
                SCAN_CELL(ix, iy, iz)
            }
        }
    }
#undef SCAN_CELL

    float bu = best;
    bu = fminf(bu, __shfl_xor(bu, 1, QL));
    bu = fminf(bu, __shfl_xor(bu, 2, QL));
    bu = fminf(bu, __shfl_xor(bu, 4, QL));
    bu = fminf(bu, __shfl_xor(bu, 8, QL));
    if (g == 0) out[cloud * NPTS + __float_as_int(qp.w)] = bu;
}

extern "C" void kernel_launch(void* const* d_in, const int* in_sizes, int n_in,
                              void* d_out, int out_size, void* d_ws, size_t ws_size,
                              hipStream_t stream) {
    const float* s = (const float*)d_in[0];
    const float* t = (const float*)d_in[1];

    int* wsI = (int*)d_ws;
    int* cntS   = wsI;                 // NC
    int* cntT   = wsI + NC;            // NC
    int* startS = wsI + 2 * NC;        // NC (becomes end[] after scatter)
    int* startT = wsI + 3 * NC;        // NC
    int* tab    = wsI + 4 * NC;        // 4928 (padded to 16B multiple)
    float4* sortedS = (float4*)(wsI + 4 * NC + 4928);   // NPTS
    float4* sortedT = sortedS + NPTS;                   // NPTS

    hipMemsetAsync(cntS, 0, (size_t)2 * NC * sizeof(int), stream);
    hist_k<<<(2 * NPTS) / 256, 256, 0, stream>>>(s, t, cntS, cntT);
    scan_k<<<1, 1024, 0, stream>>>(cntS, cntT, startS, startT, tab);
    scatter_k<<<(2 * NPTS) / 256, 256, 0, stream>>>(s, t, startS, startT,
                                                    sortedS, sortedT);
    query_k<<<(2 * NPTS * QL) / 256, 256, 0, stream>>>(sortedS, sortedT,
                                                       startS, startT,
                                                       cntS, cntT, tab,
                                                       (float*)d_out);
}